// Round 6
// baseline (280.698 us; speedup 1.0000x reference)
//
#include <hip/hip_runtime.h>

// PythonRenderer — packed-record gathers (float4/int4) + 3 L2-fit passes.
// R2–R5 established: pass time ≈ gathered-dwords/pixel × 4M / 256CU / 2.4GHz,
// BUT align-4 12B loads may never have emitted as dwordx3. This round packs
// every table record to 16B so each gather is ONE global_load_dwordx4:
//   repack: v2d,vn -> float4[B*V]; vi,vti -> int4[F]; vt -> float4[T]  (in d_ws)
//   pass1p: idx + vip + 3×v2dp -> depth,bary   (batch-affine XCD swizzle)
//   pass3p: idx + vip + 3×vnp + bary -> vn_img (batch-affine XCD swizzle)
//   passBp: idx + vtip + 3×vtp + bary -> uv
// Numerics: bit-exact vs numpy (epsclamp 1e-8 amplifies last-ulp ~1e16):
// fp contract off, exact left-to-right op order; repack is a pure bit-copy.
// Masked-bary reuse is exact (fm=1: b*fm==b bitwise; fm=0: uv->base, vn->0).

#define EPSV 1e-8f

__device__ __forceinline__ float epsclamp(float x) {
    return x < 0.0f ? fminf(x, -EPSV) : fmaxf(x, EPSV);
}

constexpr int Wd = 1024, Hd = 1024, Vd = 98304, Fd = 196608, Td = 131072, Bd = 4;
constexpr int NPIX = 1 << 22;          // B*H*W
constexpr int PPB  = 1 << 20;          // pixels per batch

// ---- d_ws layout (16B-aligned records) ----
constexpr size_t OFF_V2DP = 0;                               // float4[B*V]
constexpr size_t SZ_V2DP  = (size_t)Bd * Vd * 16;
constexpr size_t OFF_VNP  = OFF_V2DP + SZ_V2DP;              // float4[B*V]
constexpr size_t SZ_VNP   = (size_t)Bd * Vd * 16;
constexpr size_t OFF_VIP  = OFF_VNP + SZ_VNP;                // int4[F]
constexpr size_t SZ_VIP   = (size_t)Fd * 16;
constexpr size_t OFF_VTIP = OFF_VIP + SZ_VIP;                // int4[F]
constexpr size_t SZ_VTIP  = (size_t)Fd * 16;
constexpr size_t OFF_VTP  = OFF_VTIP + SZ_VTIP;              // float4[T]
constexpr size_t SZ_VTP   = (size_t)Td * 16;
constexpr size_t WS_NEED  = OFF_VTP + SZ_VTP;                // ~21 MB

struct I3 { int a, b, c; };
struct F3 { float x, y, z; };

// blockIdx (4096 blocks, 1024 px) -> base pixel, XCD-batch affinity
// (assumes round-robin block->XCD; perf-only). Bijective.
__device__ __forceinline__ int base_pixel_swz(int j, int tid) {
    const int xcd = j & 7;
    const int b = xcd >> 1;
    const int sub = ((j >> 3) << 1) + (j & 1);   // [0,1024)
    return b * PPB + sub * 1024 + tid * 4;
}

// ================= repack kernels (coalesced, ~8 µs total) =================
__global__ __launch_bounds__(256) void repack_vert(
    const float* __restrict__ v2d, const float* __restrict__ vn,
    float4* __restrict__ v2dp, float4* __restrict__ vnp)
{
    const int i = blockIdx.x * 256 + threadIdx.x;      // [0, B*V)
    v2dp[i] = make_float4(v2d[3 * (size_t)i], v2d[3 * (size_t)i + 1], v2d[3 * (size_t)i + 2], 0.f);
    vnp[i]  = make_float4(vn[3 * (size_t)i],  vn[3 * (size_t)i + 1],  vn[3 * (size_t)i + 2],  0.f);
}

__global__ __launch_bounds__(256) void repack_face(
    const int* __restrict__ vi, const int* __restrict__ vti,
    int4* __restrict__ vip, int4* __restrict__ vtip)
{
    const int f = blockIdx.x * 256 + threadIdx.x;      // [0, F)
    vip[f]  = make_int4(vi[3 * (size_t)f],  vi[3 * (size_t)f + 1],  vi[3 * (size_t)f + 2],  0);
    vtip[f] = make_int4(vti[3 * (size_t)f], vti[3 * (size_t)f + 1], vti[3 * (size_t)f + 2], 0);
}

__global__ __launch_bounds__(256) void repack_vt(
    const float* __restrict__ vt, float4* __restrict__ vtp)
{
    const int t = blockIdx.x * 256 + threadIdx.x;      // [0, T)
    vtp[t] = make_float4(vt[2 * (size_t)t], vt[2 * (size_t)t + 1], 0.f, 0.f);
}

// ================= packed pixel passes =================
__global__ __launch_bounds__(256) void pass1p(
    const float4* __restrict__ v2dp, const int4* __restrict__ vip,
    const int* __restrict__ index_img, float* __restrict__ out)
{
#pragma clang fp contract(off)
    const int pb = base_pixel_swz(blockIdx.x, threadIdx.x);
    const int b = pb >> 20;

    const int4 iv = *reinterpret_cast<const int4*>(index_img + pb);
    const int idx[4] = { iv.x, iv.y, iv.z, iv.w };

    int4 ii[4];
#pragma unroll
    for (int k = 0; k < 4; ++k) {
        const int f = idx[k] < 0 ? 0 : idx[k];
        ii[k] = vip[f];
    }

    const float4* __restrict__ vb = v2dp + (size_t)b * Vd;
    float4 P0[4], P1[4], P2[4];
#pragma unroll
    for (int k = 0; k < 4; ++k) {
        P0[k] = vb[ii[k].x];
        P1[k] = vb[ii[k].y];
        P2[k] = vb[ii[k].z];
    }

    float dep[4], b0m[4], b1m[4], b2m[4];
#pragma unroll
    for (int k = 0; k < 4; ++k) {
        const int p = pb + k;
        const int x = p & (Wd - 1);
        const int y = (p >> 10) & (Hd - 1);
        const float fm = (idx[k] != -1) ? 1.0f : 0.0f;

        const float v01x = P1[k].x - P0[k].x, v01y = P1[k].y - P0[k].y;
        const float v02x = P2[k].x - P0[k].x, v02y = P2[k].y - P0[k].y;
        const float det = (v01x * v02y) - (v01y * v02x);
        const float denom = epsclamp(det);
        const float pxr = (float)x - P0[k].x;
        const float pyr = (float)y - P0[k].y;
        const float l1 = ((pxr * v02y) - (pyr * v02x)) / denom;
        const float l2 = ((pyr * v01x) - (pxr * v01y)) / denom;
        const float l0 = (1.0f - l1) - l2;

        const float w0 = 1.0f / epsclamp(P0[k].z);
        const float w1 = 1.0f / epsclamp(P1[k].z);
        const float w2 = 1.0f / epsclamp(P2[k].z);
        const float t0w = w0 * l0;
        const float t1w = w1 * l1;
        const float t2w = w2 * l2;
        const float zsum = (t0w + t1w) + t2w;
        const float zi = 1.0f / epsclamp(zsum);

        dep[k] = zi * fm;
        b0m[k] = (t0w * zi) * fm;
        b1m[k] = (t1w * zi) * fm;
        b2m[k] = (t2w * zi) * fm;
    }

    *reinterpret_cast<float4*>(out + pb) = make_float4(dep[0], dep[1], dep[2], dep[3]);
    float* __restrict__ ob = out + (size_t)NPIX + 3 * (size_t)pb;   // 16B aligned
    reinterpret_cast<float4*>(ob)[0] = make_float4(b0m[0], b1m[0], b2m[0], b0m[1]);
    reinterpret_cast<float4*>(ob)[1] = make_float4(b1m[1], b2m[1], b0m[2], b1m[2]);
    reinterpret_cast<float4*>(ob)[2] = make_float4(b2m[2], b0m[3], b1m[3], b2m[3]);
}

__global__ __launch_bounds__(256) void pass3p(
    const float4* __restrict__ vnp, const int4* __restrict__ vip,
    const int* __restrict__ index_img, float* __restrict__ out)
{
#pragma clang fp contract(off)
    const int pb = base_pixel_swz(blockIdx.x, threadIdx.x);
    const int b = pb >> 20;

    const int4 iv = *reinterpret_cast<const int4*>(index_img + pb);
    const int idx[4] = { iv.x, iv.y, iv.z, iv.w };

    int4 ii[4];
#pragma unroll
    for (int k = 0; k < 4; ++k) {
        const int f = idx[k] < 0 ? 0 : idx[k];
        ii[k] = vip[f];
    }

    const float4* __restrict__ nb = vnp + (size_t)b * Vd;
    float4 N0[4], N1[4], N2[4];
#pragma unroll
    for (int k = 0; k < 4; ++k) {
        N0[k] = nb[ii[k].x];
        N1[k] = nb[ii[k].y];
        N2[k] = nb[ii[k].z];
    }

    const float* __restrict__ bp = out + (size_t)NPIX + 3 * (size_t)pb;
    const float4 B0 = reinterpret_cast<const float4*>(bp)[0];
    const float4 B1 = reinterpret_cast<const float4*>(bp)[1];
    const float4 B2 = reinterpret_cast<const float4*>(bp)[2];
    const float b0m[4] = { B0.x, B0.w, B1.z, B2.y };
    const float b1m[4] = { B0.y, B1.x, B1.w, B2.z };
    const float b2m[4] = { B0.z, B1.y, B2.x, B2.w };

    float vnx[4], vny[4], vnz[4];
#pragma unroll
    for (int k = 0; k < 4; ++k) {
        const float fm = (idx[k] != -1) ? 1.0f : 0.0f;
        vnx[k] = (((N0[k].x * b0m[k]) + (N1[k].x * b1m[k])) + (N2[k].x * b2m[k])) * fm;
        vny[k] = (((N0[k].y * b0m[k]) + (N1[k].y * b1m[k])) + (N2[k].y * b2m[k])) * fm;
        vnz[k] = (((N0[k].z * b0m[k]) + (N1[k].z * b1m[k])) + (N2[k].z * b2m[k])) * fm;
    }

    float* __restrict__ on = out + (size_t)NPIX * 6 + 3 * (size_t)pb;
    reinterpret_cast<float4*>(on)[0] = make_float4(vnx[0], vny[0], vnz[0], vnx[1]);
    reinterpret_cast<float4*>(on)[1] = make_float4(vny[1], vnz[1], vnx[2], vny[2]);
    reinterpret_cast<float4*>(on)[2] = make_float4(vnz[2], vnx[3], vny[3], vnz[3]);
}

__global__ __launch_bounds__(256) void passBp(
    const float4* __restrict__ vtp, const int4* __restrict__ vtip,
    const int* __restrict__ index_img, float* __restrict__ out)
{
#pragma clang fp contract(off)
    const int pb = blockIdx.x * 1024 + threadIdx.x * 4;

    const int4 iv = *reinterpret_cast<const int4*>(index_img + pb);
    const int idx[4] = { iv.x, iv.y, iv.z, iv.w };

    int4 tt[4];
#pragma unroll
    for (int k = 0; k < 4; ++k) {
        const int f = idx[k] < 0 ? 0 : idx[k];
        tt[k] = vtip[f];
    }

    float4 tA[4], tB[4], tC[4];
#pragma unroll
    for (int k = 0; k < 4; ++k) {
        tA[k] = vtp[tt[k].x];
        tB[k] = vtp[tt[k].y];
        tC[k] = vtp[tt[k].z];
    }

    const float* __restrict__ bp = out + (size_t)NPIX + 3 * (size_t)pb;
    const float4 B0 = reinterpret_cast<const float4*>(bp)[0];
    const float4 B1 = reinterpret_cast<const float4*>(bp)[1];
    const float4 B2 = reinterpret_cast<const float4*>(bp)[2];
    const float b0[4] = { B0.x, B0.w, B1.z, B2.y };
    const float b1[4] = { B0.y, B1.x, B1.w, B2.z };
    const float b2[4] = { B0.z, B1.y, B2.x, B2.w };

    float u[4], v[4];
#pragma unroll
    for (int k = 0; k < 4; ++k) {
        const int p = pb + k;
        const int x = p & (Wd - 1);
        const int y = (p >> 10) & (Hd - 1);
        const float fm = (idx[k] != -1) ? 1.0f : 0.0f;

        float vtx = ((tA[k].x * b0[k]) + (tB[k].x * b1[k])) + (tC[k].x * b2[k]);
        float vty = ((tA[k].y * b0[k]) + (tB[k].y * b1[k])) + (tC[k].y * b2[k]);

        const float bx = (((float)x * 2.0f) + 1.0f) / (float)Wd - 1.0f;
        const float by = (((float)y * 2.0f) + 1.0f) / (float)Hd - 1.0f;
        u[k] = bx + (fm * (((vtx * 2.0f) - 1.0f) - bx));
        v[k] = by + (fm * (((vty * 2.0f) - 1.0f) - by));
    }

    float* __restrict__ ov = out + (size_t)NPIX * 4 + 2 * (size_t)pb;
    reinterpret_cast<float4*>(ov)[0] = make_float4(u[0], v[0], u[1], v[1]);
    reinterpret_cast<float4*>(ov)[1] = make_float4(u[2], v[2], u[3], v[3]);
}

// ================= fallback (R5 kernels, unpacked) =================
__global__ __launch_bounds__(256) void pass1f(
    const float* __restrict__ v2d, const int* __restrict__ vi,
    const int* __restrict__ index_img, float* __restrict__ out)
{
#pragma clang fp contract(off)
    const int pb = base_pixel_swz(blockIdx.x, threadIdx.x);
    const int b = pb >> 20;
    const int4 iv = *reinterpret_cast<const int4*>(index_img + pb);
    const int idx[4] = { iv.x, iv.y, iv.z, iv.w };
    I3 ii[4];
#pragma unroll
    for (int k = 0; k < 4; ++k) {
        const int f = idx[k] < 0 ? 0 : idx[k];
        ii[k] = *reinterpret_cast<const I3*>(vi + 3 * (size_t)f);
    }
    const float* __restrict__ vb = v2d + (size_t)b * Vd * 3;
    F3 P0[4], P1[4], P2[4];
#pragma unroll
    for (int k = 0; k < 4; ++k) {
        P0[k] = *reinterpret_cast<const F3*>(vb + 3 * (size_t)ii[k].a);
        P1[k] = *reinterpret_cast<const F3*>(vb + 3 * (size_t)ii[k].b);
        P2[k] = *reinterpret_cast<const F3*>(vb + 3 * (size_t)ii[k].c);
    }
    float dep[4], b0m[4], b1m[4], b2m[4];
#pragma unroll
    for (int k = 0; k < 4; ++k) {
        const int p = pb + k;
        const int x = p & (Wd - 1);
        const int y = (p >> 10) & (Hd - 1);
        const float fm = (idx[k] != -1) ? 1.0f : 0.0f;
        const float v01x = P1[k].x - P0[k].x, v01y = P1[k].y - P0[k].y;
        const float v02x = P2[k].x - P0[k].x, v02y = P2[k].y - P0[k].y;
        const float det = (v01x * v02y) - (v01y * v02x);
        const float denom = epsclamp(det);
        const float pxr = (float)x - P0[k].x;
        const float pyr = (float)y - P0[k].y;
        const float l1 = ((pxr * v02y) - (pyr * v02x)) / denom;
        const float l2 = ((pyr * v01x) - (pxr * v01y)) / denom;
        const float l0 = (1.0f - l1) - l2;
        const float w0 = 1.0f / epsclamp(P0[k].z);
        const float w1 = 1.0f / epsclamp(P1[k].z);
        const float w2 = 1.0f / epsclamp(P2[k].z);
        const float t0w = w0 * l0, t1w = w1 * l1, t2w = w2 * l2;
        const float zsum = (t0w + t1w) + t2w;
        const float zi = 1.0f / epsclamp(zsum);
        dep[k] = zi * fm;
        b0m[k] = (t0w * zi) * fm;
        b1m[k] = (t1w * zi) * fm;
        b2m[k] = (t2w * zi) * fm;
    }
    *reinterpret_cast<float4*>(out + pb) = make_float4(dep[0], dep[1], dep[2], dep[3]);
    float* __restrict__ ob = out + (size_t)NPIX + 3 * (size_t)pb;
    reinterpret_cast<float4*>(ob)[0] = make_float4(b0m[0], b1m[0], b2m[0], b0m[1]);
    reinterpret_cast<float4*>(ob)[1] = make_float4(b1m[1], b2m[1], b0m[2], b1m[2]);
    reinterpret_cast<float4*>(ob)[2] = make_float4(b2m[2], b0m[3], b1m[3], b2m[3]);
}

__global__ __launch_bounds__(256) void pass3f(
    const float* __restrict__ vn, const int* __restrict__ vi,
    const int* __restrict__ index_img, float* __restrict__ out)
{
#pragma clang fp contract(off)
    const int pb = base_pixel_swz(blockIdx.x, threadIdx.x);
    const int b = pb >> 20;
    const int4 iv = *reinterpret_cast<const int4*>(index_img + pb);
    const int idx[4] = { iv.x, iv.y, iv.z, iv.w };
    I3 ii[4];
#pragma unroll
    for (int k = 0; k < 4; ++k) {
        const int f = idx[k] < 0 ? 0 : idx[k];
        ii[k] = *reinterpret_cast<const I3*>(vi + 3 * (size_t)f);
    }
    const float* __restrict__ nb = vn + (size_t)b * Vd * 3;
    F3 N0[4], N1[4], N2[4];
#pragma unroll
    for (int k = 0; k < 4; ++k) {
        N0[k] = *reinterpret_cast<const F3*>(nb + 3 * (size_t)ii[k].a);
        N1[k] = *reinterpret_cast<const F3*>(nb + 3 * (size_t)ii[k].b);
        N2[k] = *reinterpret_cast<const F3*>(nb + 3 * (size_t)ii[k].c);
    }
    const float* __restrict__ bp = out + (size_t)NPIX + 3 * (size_t)pb;
    const float4 B0 = reinterpret_cast<const float4*>(bp)[0];
    const float4 B1 = reinterpret_cast<const float4*>(bp)[1];
    const float4 B2 = reinterpret_cast<const float4*>(bp)[2];
    const float b0m[4] = { B0.x, B0.w, B1.z, B2.y };
    const float b1m[4] = { B0.y, B1.x, B1.w, B2.z };
    const float b2m[4] = { B0.z, B1.y, B2.x, B2.w };
    float vnx[4], vny[4], vnz[4];
#pragma unroll
    for (int k = 0; k < 4; ++k) {
        const float fm = (idx[k] != -1) ? 1.0f : 0.0f;
        vnx[k] = (((N0[k].x * b0m[k]) + (N1[k].x * b1m[k])) + (N2[k].x * b2m[k])) * fm;
        vny[k] = (((N0[k].y * b0m[k]) + (N1[k].y * b1m[k])) + (N2[k].y * b2m[k])) * fm;
        vnz[k] = (((N0[k].z * b0m[k]) + (N1[k].z * b1m[k])) + (N2[k].z * b2m[k])) * fm;
    }
    float* __restrict__ on = out + (size_t)NPIX * 6 + 3 * (size_t)pb;
    reinterpret_cast<float4*>(on)[0] = make_float4(vnx[0], vny[0], vnz[0], vnx[1]);
    reinterpret_cast<float4*>(on)[1] = make_float4(vny[1], vnz[1], vnx[2], vny[2]);
    reinterpret_cast<float4*>(on)[2] = make_float4(vnz[2], vnx[3], vny[3], vnz[3]);
}

__global__ __launch_bounds__(256) void passBf(
    const float* __restrict__ vt, const int* __restrict__ vti,
    const int* __restrict__ index_img, float* __restrict__ out)
{
#pragma clang fp contract(off)
    const int pb = blockIdx.x * 1024 + threadIdx.x * 4;
    const int4 iv = *reinterpret_cast<const int4*>(index_img + pb);
    const int idx[4] = { iv.x, iv.y, iv.z, iv.w };
    I3 tt[4];
#pragma unroll
    for (int k = 0; k < 4; ++k) {
        const int f = idx[k] < 0 ? 0 : idx[k];
        tt[k] = *reinterpret_cast<const I3*>(vti + 3 * (size_t)f);
    }
    const float2* __restrict__ vt2 = reinterpret_cast<const float2*>(vt);
    float2 tA[4], tB[4], tC[4];
#pragma unroll
    for (int k = 0; k < 4; ++k) {
        tA[k] = vt2[tt[k].a];
        tB[k] = vt2[tt[k].b];
        tC[k] = vt2[tt[k].c];
    }
    const float* __restrict__ bp = out + (size_t)NPIX + 3 * (size_t)pb;
    const float4 B0 = reinterpret_cast<const float4*>(bp)[0];
    const float4 B1 = reinterpret_cast<const float4*>(bp)[1];
    const float4 B2 = reinterpret_cast<const float4*>(bp)[2];
    const float b0[4] = { B0.x, B0.w, B1.z, B2.y };
    const float b1[4] = { B0.y, B1.x, B1.w, B2.z };
    const float b2[4] = { B0.z, B1.y, B2.x, B2.w };
    float u[4], v[4];
#pragma unroll
    for (int k = 0; k < 4; ++k) {
        const int p = pb + k;
        const int x = p & (Wd - 1);
        const int y = (p >> 10) & (Hd - 1);
        const float fm = (idx[k] != -1) ? 1.0f : 0.0f;
        float vtx = ((tA[k].x * b0[k]) + (tB[k].x * b1[k])) + (tC[k].x * b2[k]);
        float vty = ((tA[k].y * b0[k]) + (tB[k].y * b1[k])) + (tC[k].y * b2[k]);
        const float bx = (((float)x * 2.0f) + 1.0f) / (float)Wd - 1.0f;
        const float by = (((float)y * 2.0f) + 1.0f) / (float)Hd - 1.0f;
        u[k] = bx + (fm * (((vtx * 2.0f) - 1.0f) - bx));
        v[k] = by + (fm * (((vty * 2.0f) - 1.0f) - by));
    }
    float* __restrict__ ov = out + (size_t)NPIX * 4 + 2 * (size_t)pb;
    reinterpret_cast<float4*>(ov)[0] = make_float4(u[0], v[0], u[1], v[1]);
    reinterpret_cast<float4*>(ov)[1] = make_float4(u[2], v[2], u[3], v[3]);
}

extern "C" void kernel_launch(void* const* d_in, const int* in_sizes, int n_in,
                              void* d_out, int out_size, void* d_ws, size_t ws_size,
                              hipStream_t stream) {
    const float* v2d       = (const float*)d_in[0];
    const float* vt        = (const float*)d_in[1];
    const int*   vi        = (const int*)d_in[2];
    const int*   vti       = (const int*)d_in[3];
    const int*   index_img = (const int*)d_in[4];
    const float* vn        = (const float*)d_in[5];
    float* out = (float*)d_out;

    dim3 block(256);
    dim3 gridPx(NPIX / 1024);                    // 4 px/thread

    if (ws_size >= WS_NEED) {
        char* ws = (char*)d_ws;
        float4* v2dp = (float4*)(ws + OFF_V2DP);
        float4* vnp  = (float4*)(ws + OFF_VNP);
        int4*   vip  = (int4*)(ws + OFF_VIP);
        int4*   vtip = (int4*)(ws + OFF_VTIP);
        float4* vtp  = (float4*)(ws + OFF_VTP);

        repack_vert<<<dim3(Bd * Vd / 256), block, 0, stream>>>(v2d, vn, v2dp, vnp);
        repack_face<<<dim3(Fd / 256), block, 0, stream>>>(vi, vti, vip, vtip);
        repack_vt  <<<dim3(Td / 256), block, 0, stream>>>(vt, vtp);

        pass1p<<<gridPx, block, 0, stream>>>(v2dp, vip, index_img, out);
        passBp<<<gridPx, block, 0, stream>>>(vtp, vtip, index_img, out);
        pass3p<<<gridPx, block, 0, stream>>>(vnp, vip, index_img, out);
    } else {
        pass1f<<<gridPx, block, 0, stream>>>(v2d, vi, index_img, out);
        passBf<<<gridPx, block, 0, stream>>>(vt, vti, index_img, out);
        pass3f<<<gridPx, block, 0, stream>>>(vn, vi, index_img, out);
    }
}

// Round 7
// 241.457 us; speedup vs baseline: 1.1625x; 1.1625x over previous
//
#include <hip/hip_runtime.h>

// PythonRenderer R6 — DISCRIMINATOR: per-dword vs per-line TA cost model.
//   passAx: fused depth+bary+vn; vi via 3 scalar dwords; v2d/vn via
//           GUARANTEED dwordx4 gathers from repacked float4 tables
//           (1 px/thread, all loads hoisted, target ~60 VGPR so nothing
//           serializes — fixes R6-prev's VGPR=32 confound).
//   passBf: best-known uv pass (R5 form, ~59 µs).
// Per-line model → passAx ~90 µs; per-dword model → passAx ~210 µs.
// Numerics: bit-exact vs numpy (epsclamp 1e-8 amplifies last-ulp ~1e16):
// fp contract off, exact left-to-right op order; repack is a bit-copy.

#define EPSV 1e-8f

__device__ __forceinline__ float epsclamp(float x) {
    return x < 0.0f ? fminf(x, -EPSV) : fmaxf(x, EPSV);
}

constexpr int Wd = 1024, Hd = 1024, Vd = 98304, Fd = 196608, Bd = 4;
constexpr int NPIX = 1 << 22;
constexpr int PPB  = 1 << 20;

// ws: float4 v2dp[B*V] @0 (6MB), float4 vnp[B*V] @6MB. ~12.6MB total.
constexpr size_t OFF_V2DP = 0;
constexpr size_t SZ_V2DP  = (size_t)Bd * Vd * 16;
constexpr size_t OFF_VNP  = OFF_V2DP + SZ_V2DP;
constexpr size_t SZ_VNP   = (size_t)Bd * Vd * 16;
constexpr size_t WS_NEED  = OFF_VNP + SZ_VNP;

struct I3 { int a, b, c; };
struct F3 { float x, y, z; };

// 16384 blocks × 256 threads, 1 px/thread; batch-affine XCD swizzle.
__device__ __forceinline__ int swizzled_pixel(int j, int tid) {
    const int xcd = j & 7;
    const int b = xcd >> 1;
    const int sub = ((j >> 3) << 1) + (j & 1);   // [0,4096)
    return b * PPB + sub * 256 + tid;
}

__global__ __launch_bounds__(256) void repack_vert(
    const float* __restrict__ v2d, const float* __restrict__ vn,
    float4* __restrict__ v2dp, float4* __restrict__ vnp)
{
    const int i = blockIdx.x * 256 + threadIdx.x;      // [0, B*V)
    v2dp[i] = make_float4(v2d[3 * (size_t)i], v2d[3 * (size_t)i + 1], v2d[3 * (size_t)i + 2], 0.f);
    vnp[i]  = make_float4(vn[3 * (size_t)i],  vn[3 * (size_t)i + 1],  vn[3 * (size_t)i + 2],  0.f);
}

// ---------------- passAx: fused depth + bary + vn (EXPERIMENT) ----------------
__global__ __launch_bounds__(256) void passAx(
    const float4* __restrict__ v2dp, const float4* __restrict__ vnp,
    const int* __restrict__ vi,
    const int* __restrict__ index_img, float* __restrict__ out)
{
#pragma clang fp contract(off)
    const int p = swizzled_pixel(blockIdx.x, threadIdx.x);
    const int x = p & (Wd - 1);
    const int y = (p >> 10) & (Hd - 1);
    const int b = p >> 20;

    const int idx = index_img[p];
    const float fm = (idx != -1) ? 1.0f : 0.0f;
    const int f = (idx < 0) ? 0 : idx;

    // 3 contiguous dword loads (compiler may merge to x3 — fine either way)
    const int i0 = vi[3 * (size_t)f + 0];
    const int i1 = vi[3 * (size_t)f + 1];
    const int i2 = vi[3 * (size_t)f + 2];

    // 6 guaranteed dwordx4 gathers, all issued before any use
    const float4* __restrict__ vb = v2dp + (size_t)b * Vd;
    const float4* __restrict__ nb = vnp + (size_t)b * Vd;
    const float4 P0 = vb[i0];
    const float4 P1 = vb[i1];
    const float4 P2 = vb[i2];
    const float4 N0 = nb[i0];
    const float4 N1 = nb[i1];
    const float4 N2 = nb[i2];

    // --- bit-exact math (numpy order, no contraction) ---
    const float v01x = P1.x - P0.x, v01y = P1.y - P0.y;
    const float v02x = P2.x - P0.x, v02y = P2.y - P0.y;
    const float det = (v01x * v02y) - (v01y * v02x);
    const float denom = epsclamp(det);
    const float pxr = (float)x - P0.x;
    const float pyr = (float)y - P0.y;
    const float l1 = ((pxr * v02y) - (pyr * v02x)) / denom;
    const float l2 = ((pyr * v01x) - (pxr * v01y)) / denom;
    const float l0 = (1.0f - l1) - l2;

    const float w0 = 1.0f / epsclamp(P0.z);
    const float w1 = 1.0f / epsclamp(P1.z);
    const float w2 = 1.0f / epsclamp(P2.z);
    const float t0w = w0 * l0;
    const float t1w = w1 * l1;
    const float t2w = w2 * l2;
    const float zsum = (t0w + t1w) + t2w;
    const float zi = 1.0f / epsclamp(zsum);

    const float b0m = (t0w * zi) * fm;
    const float b1m = (t1w * zi) * fm;
    const float b2m = (t2w * zi) * fm;

    const float vnx = (((N0.x * b0m) + (N1.x * b1m)) + (N2.x * b2m)) * fm;
    const float vny = (((N0.y * b0m) + (N1.y * b1m)) + (N2.y * b2m)) * fm;
    const float vnz = (((N0.z * b0m) + (N1.z * b1m)) + (N2.z * b2m)) * fm;

    out[p] = zi * fm;
    float* __restrict__ ob = out + (size_t)NPIX;
    ob[3 * (size_t)p + 0] = b0m;
    ob[3 * (size_t)p + 1] = b1m;
    ob[3 * (size_t)p + 2] = b2m;
    float* __restrict__ on = out + (size_t)NPIX * 6;
    on[3 * (size_t)p + 0] = vnx;
    on[3 * (size_t)p + 1] = vny;
    on[3 * (size_t)p + 2] = vnz;
}

// ---------------- passAf: fallback (R4 passA, unpacked) ----------------
__global__ __launch_bounds__(256) void passAf(
    const float* __restrict__ v2d, const int* __restrict__ vi,
    const int* __restrict__ index_img, const float* __restrict__ vn,
    float* __restrict__ out)
{
#pragma clang fp contract(off)
    const int p = swizzled_pixel(blockIdx.x, threadIdx.x);
    const int x = p & (Wd - 1);
    const int y = (p >> 10) & (Hd - 1);
    const int b = p >> 20;

    const int idx = index_img[p];
    const float fm = (idx != -1) ? 1.0f : 0.0f;
    const int f = (idx < 0) ? 0 : idx;

    const I3 ii = *reinterpret_cast<const I3*>(vi + 3 * (size_t)f);
    const float* __restrict__ vb = v2d + (size_t)b * Vd * 3;
    const F3 P0 = *reinterpret_cast<const F3*>(vb + 3 * (size_t)ii.a);
    const F3 P1 = *reinterpret_cast<const F3*>(vb + 3 * (size_t)ii.b);
    const F3 P2 = *reinterpret_cast<const F3*>(vb + 3 * (size_t)ii.c);
    const float* __restrict__ nb = vn + (size_t)b * Vd * 3;
    const F3 N0 = *reinterpret_cast<const F3*>(nb + 3 * (size_t)ii.a);
    const F3 N1 = *reinterpret_cast<const F3*>(nb + 3 * (size_t)ii.b);
    const F3 N2 = *reinterpret_cast<const F3*>(nb + 3 * (size_t)ii.c);

    const float v01x = P1.x - P0.x, v01y = P1.y - P0.y;
    const float v02x = P2.x - P0.x, v02y = P2.y - P0.y;
    const float det = (v01x * v02y) - (v01y * v02x);
    const float denom = epsclamp(det);
    const float pxr = (float)x - P0.x;
    const float pyr = (float)y - P0.y;
    const float l1 = ((pxr * v02y) - (pyr * v02x)) / denom;
    const float l2 = ((pyr * v01x) - (pxr * v01y)) / denom;
    const float l0 = (1.0f - l1) - l2;
    const float w0 = 1.0f / epsclamp(P0.z);
    const float w1 = 1.0f / epsclamp(P1.z);
    const float w2 = 1.0f / epsclamp(P2.z);
    const float t0w = w0 * l0, t1w = w1 * l1, t2w = w2 * l2;
    const float zsum = (t0w + t1w) + t2w;
    const float zi = 1.0f / epsclamp(zsum);
    const float b0m = (t0w * zi) * fm;
    const float b1m = (t1w * zi) * fm;
    const float b2m = (t2w * zi) * fm;
    const float vnx = (((N0.x * b0m) + (N1.x * b1m)) + (N2.x * b2m)) * fm;
    const float vny = (((N0.y * b0m) + (N1.y * b1m)) + (N2.y * b2m)) * fm;
    const float vnz = (((N0.z * b0m) + (N1.z * b1m)) + (N2.z * b2m)) * fm;

    out[p] = zi * fm;
    float* __restrict__ ob = out + (size_t)NPIX;
    ob[3 * (size_t)p + 0] = b0m;
    ob[3 * (size_t)p + 1] = b1m;
    ob[3 * (size_t)p + 2] = b2m;
    float* __restrict__ on = out + (size_t)NPIX * 6;
    on[3 * (size_t)p + 0] = vnx;
    on[3 * (size_t)p + 1] = vny;
    on[3 * (size_t)p + 2] = vnz;
}

// ---------------- passBf: uv (best-known, R5 form) ----------------
__global__ __launch_bounds__(256) void passBf(
    const float* __restrict__ vt, const int* __restrict__ vti,
    const int* __restrict__ index_img, float* __restrict__ out)
{
#pragma clang fp contract(off)
    const int pb = blockIdx.x * 1024 + threadIdx.x * 4;
    const int4 iv = *reinterpret_cast<const int4*>(index_img + pb);
    const int idx[4] = { iv.x, iv.y, iv.z, iv.w };
    I3 tt[4];
#pragma unroll
    for (int k = 0; k < 4; ++k) {
        const int f = idx[k] < 0 ? 0 : idx[k];
        tt[k] = *reinterpret_cast<const I3*>(vti + 3 * (size_t)f);
    }
    const float2* __restrict__ vt2 = reinterpret_cast<const float2*>(vt);
    float2 tA[4], tB[4], tC[4];
#pragma unroll
    for (int k = 0; k < 4; ++k) {
        tA[k] = vt2[tt[k].a];
        tB[k] = vt2[tt[k].b];
        tC[k] = vt2[tt[k].c];
    }
    const float* __restrict__ bp = out + (size_t)NPIX + 3 * (size_t)pb;
    const float4 B0 = reinterpret_cast<const float4*>(bp)[0];
    const float4 B1 = reinterpret_cast<const float4*>(bp)[1];
    const float4 B2 = reinterpret_cast<const float4*>(bp)[2];
    const float b0[4] = { B0.x, B0.w, B1.z, B2.y };
    const float b1[4] = { B0.y, B1.x, B1.w, B2.z };
    const float b2[4] = { B0.z, B1.y, B2.x, B2.w };
    float u[4], v[4];
#pragma unroll
    for (int k = 0; k < 4; ++k) {
        const int p = pb + k;
        const int x = p & (Wd - 1);
        const int y = (p >> 10) & (Hd - 1);
        const float fm = (idx[k] != -1) ? 1.0f : 0.0f;
        float vtx = ((tA[k].x * b0[k]) + (tB[k].x * b1[k])) + (tC[k].x * b2[k]);
        float vty = ((tA[k].y * b0[k]) + (tB[k].y * b1[k])) + (tC[k].y * b2[k]);
        const float bx = (((float)x * 2.0f) + 1.0f) / (float)Wd - 1.0f;
        const float by = (((float)y * 2.0f) + 1.0f) / (float)Hd - 1.0f;
        u[k] = bx + (fm * (((vtx * 2.0f) - 1.0f) - bx));
        v[k] = by + (fm * (((vty * 2.0f) - 1.0f) - by));
    }
    float* __restrict__ ov = out + (size_t)NPIX * 4 + 2 * (size_t)pb;
    reinterpret_cast<float4*>(ov)[0] = make_float4(u[0], v[0], u[1], v[1]);
    reinterpret_cast<float4*>(ov)[1] = make_float4(u[2], v[2], u[3], v[3]);
}

extern "C" void kernel_launch(void* const* d_in, const int* in_sizes, int n_in,
                              void* d_out, int out_size, void* d_ws, size_t ws_size,
                              hipStream_t stream) {
    const float* v2d       = (const float*)d_in[0];
    const float* vt        = (const float*)d_in[1];
    const int*   vi        = (const int*)d_in[2];
    const int*   vti       = (const int*)d_in[3];
    const int*   index_img = (const int*)d_in[4];
    const float* vn        = (const float*)d_in[5];
    float* out = (float*)d_out;

    dim3 block(256);

    if (ws_size >= WS_NEED) {
        char* ws = (char*)d_ws;
        float4* v2dp = (float4*)(ws + OFF_V2DP);
        float4* vnp  = (float4*)(ws + OFF_VNP);
        repack_vert<<<dim3(Bd * Vd / 256), block, 0, stream>>>(v2d, vn, v2dp, vnp);
        passAx<<<dim3(NPIX / 256), block, 0, stream>>>(v2dp, vnp, vi, index_img, out);
    } else {
        passAf<<<dim3(NPIX / 256), block, 0, stream>>>(v2d, vi, index_img, vn, out);
    }
    passBf<<<dim3(NPIX / 1024), block, 0, stream>>>(vt, vti, index_img, out);
}

// Round 8
// 222.423 us; speedup vs baseline: 1.2620x; 1.0856x over previous
//
#include <hip/hip_runtime.h>

// PythonRenderer R7 — MLP-forcing experiment on the best-known layout (R4).
//   passA_mlp: fused depth+bary+vn, UNPADDED tables (set 4.6MB/XCD,
//              batch-affine swizzle), launch_bounds(256,1) + asm value-fence
//              so ALL 21 gathered dwords are issued before any use.
//   passB_mlp: uv pass (R5 form, 4px/thread) + same fence.
// Discriminates "gathers serialized by VGPR starvation" (→ ~150µs total)
// vs "TCP per-dword throughput bound" (→ unchanged ~219µs total).
// Numerics: bit-exact vs numpy (epsclamp 1e-8 amplifies last-ulp ~1e16 on
// degenerate tris): fp contract off, exact left-to-right op order.
// Masked-bary reuse in passB is exact (fm=1: b*fm==b bitwise; fm=0: uv->base).

#define EPSV 1e-8f

__device__ __forceinline__ float epsclamp(float x) {
    return x < 0.0f ? fminf(x, -EPSV) : fmaxf(x, EPSV);
}

constexpr int Wd = 1024, Hd = 1024, Vd = 98304;
constexpr int NPIX = 1 << 22;
constexpr int PPB  = 1 << 20;

struct I3 { int a, b, c; };
struct F3 { float x, y, z; };

// 16384 blocks × 256 threads, 1 px/thread; batch-affine XCD swizzle
// (assumes round-robin block->XCD; perf-only). Bijective.
__device__ __forceinline__ int swizzled_pixel(int j, int tid) {
    const int xcd = j & 7;
    const int b = xcd >> 1;
    const int sub = ((j >> 3) << 1) + (j & 1);   // [0,4096)
    return b * PPB + sub * 256 + tid;
}

// ---------------- passA_mlp: fused depth + bary + vn ----------------
__global__ __launch_bounds__(256, 1) void passA_mlp(
    const float* __restrict__ v2d, const int* __restrict__ vi,
    const int* __restrict__ index_img, const float* __restrict__ vn,
    float* __restrict__ out)
{
#pragma clang fp contract(off)
    const int p = swizzled_pixel(blockIdx.x, threadIdx.x);
    const int x = p & (Wd - 1);
    const int y = (p >> 10) & (Hd - 1);
    const int b = p >> 20;

    const int idx = index_img[p];
    const float fm = (idx != -1) ? 1.0f : 0.0f;
    const int f = (idx < 0) ? 0 : idx;

    const int i0 = vi[3 * (size_t)f + 0];
    const int i1 = vi[3 * (size_t)f + 1];
    const int i2 = vi[3 * (size_t)f + 2];

    const float* __restrict__ vb = v2d + (size_t)b * Vd * 3;
    const float* __restrict__ nb = vn + (size_t)b * Vd * 3;
    const F3 P0 = *reinterpret_cast<const F3*>(vb + 3 * (size_t)i0);
    const F3 P1 = *reinterpret_cast<const F3*>(vb + 3 * (size_t)i1);
    const F3 P2 = *reinterpret_cast<const F3*>(vb + 3 * (size_t)i2);
    const F3 N0 = *reinterpret_cast<const F3*>(nb + 3 * (size_t)i0);
    const F3 N1 = *reinterpret_cast<const F3*>(nb + 3 * (size_t)i1);
    const F3 N2 = *reinterpret_cast<const F3*>(nb + 3 * (size_t)i2);

    // Value fence: force all 18 gathered floats live HERE -> loads cannot be
    // sunk into the math; all issue back-to-back, one waitcnt.
    asm volatile("" ::
        "v"(P0.x), "v"(P0.y), "v"(P0.z),
        "v"(P1.x), "v"(P1.y), "v"(P1.z),
        "v"(P2.x), "v"(P2.y), "v"(P2.z),
        "v"(N0.x), "v"(N0.y), "v"(N0.z),
        "v"(N1.x), "v"(N1.y), "v"(N1.z),
        "v"(N2.x), "v"(N2.y), "v"(N2.z));

    // --- bit-exact math (numpy order, no contraction) ---
    const float v01x = P1.x - P0.x, v01y = P1.y - P0.y;
    const float v02x = P2.x - P0.x, v02y = P2.y - P0.y;
    const float det = (v01x * v02y) - (v01y * v02x);
    const float denom = epsclamp(det);
    const float pxr = (float)x - P0.x;
    const float pyr = (float)y - P0.y;
    const float l1 = ((pxr * v02y) - (pyr * v02x)) / denom;
    const float l2 = ((pyr * v01x) - (pxr * v01y)) / denom;
    const float l0 = (1.0f - l1) - l2;

    const float w0 = 1.0f / epsclamp(P0.z);
    const float w1 = 1.0f / epsclamp(P1.z);
    const float w2 = 1.0f / epsclamp(P2.z);
    const float t0w = w0 * l0;
    const float t1w = w1 * l1;
    const float t2w = w2 * l2;
    const float zsum = (t0w + t1w) + t2w;
    const float zi = 1.0f / epsclamp(zsum);

    const float b0m = (t0w * zi) * fm;
    const float b1m = (t1w * zi) * fm;
    const float b2m = (t2w * zi) * fm;

    const float vnx = (((N0.x * b0m) + (N1.x * b1m)) + (N2.x * b2m)) * fm;
    const float vny = (((N0.y * b0m) + (N1.y * b1m)) + (N2.y * b2m)) * fm;
    const float vnz = (((N0.z * b0m) + (N1.z * b1m)) + (N2.z * b2m)) * fm;

    out[p] = zi * fm;
    float* __restrict__ ob = out + (size_t)NPIX;
    ob[3 * (size_t)p + 0] = b0m;
    ob[3 * (size_t)p + 1] = b1m;
    ob[3 * (size_t)p + 2] = b2m;
    float* __restrict__ on = out + (size_t)NPIX * 6;
    on[3 * (size_t)p + 0] = vnx;
    on[3 * (size_t)p + 1] = vny;
    on[3 * (size_t)p + 2] = vnz;
}

// ---------------- passB_mlp: uv (R5 form + fence) ----------------
__global__ __launch_bounds__(256, 1) void passB_mlp(
    const float* __restrict__ vt, const int* __restrict__ vti,
    const int* __restrict__ index_img, float* __restrict__ out)
{
#pragma clang fp contract(off)
    const int pb = blockIdx.x * 1024 + threadIdx.x * 4;
    const int4 iv = *reinterpret_cast<const int4*>(index_img + pb);
    const int idx[4] = { iv.x, iv.y, iv.z, iv.w };
    I3 tt[4];
#pragma unroll
    for (int k = 0; k < 4; ++k) {
        const int f = idx[k] < 0 ? 0 : idx[k];
        tt[k] = *reinterpret_cast<const I3*>(vti + 3 * (size_t)f);
    }
    const float2* __restrict__ vt2 = reinterpret_cast<const float2*>(vt);
    float2 tA[4], tB[4], tC[4];
#pragma unroll
    for (int k = 0; k < 4; ++k) {
        tA[k] = vt2[tt[k].a];
        tB[k] = vt2[tt[k].b];
        tC[k] = vt2[tt[k].c];
    }
#pragma unroll
    for (int k = 0; k < 4; ++k) {
        asm volatile("" ::
            "v"(tA[k].x), "v"(tA[k].y),
            "v"(tB[k].x), "v"(tB[k].y),
            "v"(tC[k].x), "v"(tC[k].y));
    }
    const float* __restrict__ bp = out + (size_t)NPIX + 3 * (size_t)pb;
    const float4 B0 = reinterpret_cast<const float4*>(bp)[0];
    const float4 B1 = reinterpret_cast<const float4*>(bp)[1];
    const float4 B2 = reinterpret_cast<const float4*>(bp)[2];
    const float b0[4] = { B0.x, B0.w, B1.z, B2.y };
    const float b1[4] = { B0.y, B1.x, B1.w, B2.z };
    const float b2[4] = { B0.z, B1.y, B2.x, B2.w };
    float u[4], v[4];
#pragma unroll
    for (int k = 0; k < 4; ++k) {
        const int p = pb + k;
        const int x = p & (Wd - 1);
        const int y = (p >> 10) & (Hd - 1);
        const float fm = (idx[k] != -1) ? 1.0f : 0.0f;
        float vtx = ((tA[k].x * b0[k]) + (tB[k].x * b1[k])) + (tC[k].x * b2[k]);
        float vty = ((tA[k].y * b0[k]) + (tB[k].y * b1[k])) + (tC[k].y * b2[k]);
        const float bx = (((float)x * 2.0f) + 1.0f) / (float)Wd - 1.0f;
        const float by = (((float)y * 2.0f) + 1.0f) / (float)Hd - 1.0f;
        u[k] = bx + (fm * (((vtx * 2.0f) - 1.0f) - bx));
        v[k] = by + (fm * (((vty * 2.0f) - 1.0f) - by));
    }
    float* __restrict__ ov = out + (size_t)NPIX * 4 + 2 * (size_t)pb;
    reinterpret_cast<float4*>(ov)[0] = make_float4(u[0], v[0], u[1], v[1]);
    reinterpret_cast<float4*>(ov)[1] = make_float4(u[2], v[2], u[3], v[3]);
}

extern "C" void kernel_launch(void* const* d_in, const int* in_sizes, int n_in,
                              void* d_out, int out_size, void* d_ws, size_t ws_size,
                              hipStream_t stream) {
    const float* v2d       = (const float*)d_in[0];
    const float* vt        = (const float*)d_in[1];
    const int*   vi        = (const int*)d_in[2];
    const int*   vti       = (const int*)d_in[3];
    const int*   index_img = (const int*)d_in[4];
    const float* vn        = (const float*)d_in[5];
    float* out = (float*)d_out;

    dim3 block(256);
    passA_mlp<<<dim3(NPIX / 256), block, 0, stream>>>(v2d, vi, index_img, vn, out);
    passB_mlp<<<dim3(NPIX / 1024), block, 0, stream>>>(vt, vti, index_img, out);
}